// Round 10
// baseline (49.455 us; speedup 1.0000x reference)
//
#include <hip/hip_runtime.h>

#define ODE_UNFOLDS 6
#define LTC_EPS 1e-8f

// TWIN-BATCH chains per lane, pk-packed. Lane owns unit u = j + h*d for TWO
// batches (b1, b2 = b1 + ceil(B/2)); adjacent lanes (h=0,1) hold the coupled
// pair {j, j+d} and exchange cross-exps via quad_perm DPP (lane XOR 1).
// All per-unit constants are shared by the two chains -> every full-rate op
// is one v_pk_* instruction processing both chains; the 4 exps + 2 rcps are
// independent scalars whose latencies overlap.
//
// Per-chain math = R8 (verified, absmax 9.8e-4): wiring identity erev=-mask,
// serev=+smask gives num' = (t+db)*P - den' with P=(1+es)(1+ex), and
//   den' = K0 + Ks*es + Kx*ex + db*es*ex   (Horner by late ex)
// Base block (sensory) pipelined one timestep ahead.

typedef float v2f __attribute__((ext_vector_type(2)));

__device__ __forceinline__ float swap_pair(float x) {
    // quad_perm [1,0,3,2] : lane XOR 1, full-rate v_mov_b32 dpp
    return __int_as_float(
        __builtin_amdgcn_mov_dpp(__float_as_int(x), 0xB1, 0xF, 0xF, true));
}

struct Base2 { v2f db, nbdb, K0, Ks, Kx; };

__global__ __launch_bounds__(64)
void ltc_twin_kernel(const float* __restrict__ inputs,
                     const float* __restrict__ input_w, const float* __restrict__ input_b,
                     const float* __restrict__ output_w, const float* __restrict__ output_b,
                     const float* __restrict__ gleak, const float* __restrict__ vleak,
                     const float* __restrict__ cm,
                     const float* __restrict__ w, const float* __restrict__ mu,
                     const float* __restrict__ sigma, const float* __restrict__ erev,
                     const float* __restrict__ sw, const float* __restrict__ smu,
                     const float* __restrict__ ssig, const float* __restrict__ serev,
                     float* __restrict__ out,
                     int B, int T, int d)
{
    const int Bh = (B + 1) >> 1;           // chains per lane cover b and b+Bh
    const int units = 2 * d;
    const int tid = blockIdx.x * blockDim.x + threadIdx.x;
    if (tid >= Bh * units) return;

    const int pairIdx = tid >> 1;
    const int h = tid & 1;                 // 0 -> unit j, 1 -> unit j+d
    const int b1 = pairIdx / d;
    const int j  = pairIdx - b1 * d;
    int b2 = b1 + Bh; if (b2 >= B) b2 = B - 1;   // (benign dup if B odd)
    const int u  = j + h * d;              // my unit
    const int pu = j + (1 - h) * d;        // partner unit

    const float LOG2E = 1.4426950408889634f;

    // self synapse u->u
    float A_s, C_s, W_s;
    {
        int i = u * units + u;
        float sg = sigma[i], m = mu[i];
        A_s = -sg * LOG2E; C_s = m * sg * LOG2E;
        W_s = w[i] * (-erev[i]);           // = +W (erev = -1 here)
    }
    // incoming cross synapse pu->u
    float W_c;
    {
        int i = pu * units + u;
        W_c = w[i] * (-erev[i]);
    }
    // outgoing cross synapse u->pu (exp evaluated from own v, partner DPPs it)
    float A_o, C_o;
    {
        int i = u * units + pu;
        float sg = sigma[i], m = mu[i];
        A_o = -sg * LOG2E; C_o = m * sg * LOG2E;
    }
    const float Wsum = W_s + W_c;

    // sensory synapse j -> u (serev = +1), input affine folded in
    float siA, siC, sW;
    {
        int i = j * units + u;
        float sg = ssig[i], m = smu[i];
        float sA = -sg * LOG2E, sC = m * sg * LOG2E;
        const float iw = input_w[j], ib = input_b[j];
        siA = iw * sA; siC = ib * sA + sC;
        sW = sw[i] * serev[i];
    }

    const float cmu = cm[u] * (float)ODE_UNFOLDS;
    const float gl  = gleak[u];
    const float gv  = gl * vleak[u];
    const float den0 = cmu + gl + LTC_EPS;
    const float sW2 = 2.f * sW;
    const float gvden0 = gv + den0;

    // broadcast v2f constants (compiler lowers to op_sel broadcasts)
    const v2f cmuV = {cmu, cmu};
    const v2f AsV = {A_s, A_s}, CsV = {C_s, C_s};
    const v2f AoV = {A_o, A_o}, CoV = {C_o, C_o};

    const float* __restrict__ xin1 = inputs + (size_t)b1 * T * d + j;
    const float* __restrict__ xin2 = inputs + (size_t)b2 * T * d + j;

    auto make_base = [&](float xa, float xb) -> Base2 {
        const float ea = __builtin_amdgcn_exp2f(fmaf(xa, siA, siC));
        const float eb = __builtin_amdgcn_exp2f(fmaf(xb, siA, siC));
        const float sa = __builtin_amdgcn_rcpf(1.f + ea);
        const float sb = __builtin_amdgcn_rcpf(1.f + eb);
        const v2f ss = {sa, sb};
        Base2 bb;
        bb.db   = __builtin_elementwise_fma(v2f{sW, sW},  ss, v2f{den0, den0});
        bb.nbdb = __builtin_elementwise_fma(v2f{sW2, sW2}, ss, v2f{gvden0, gvden0});
        bb.K0 = bb.db + v2f{Wsum, Wsum};
        bb.Ks = bb.db + v2f{W_c, W_c};
        bb.Kx = bb.db + v2f{W_s, W_s};
        return bb;
    };

    // recurrence state per chain: v = num * r
    v2f num = {0.f, 0.f};
    v2f r   = {1.f, 1.f};

    const int TU = 4;
    float xb1[TU], xb2[TU];
#pragma unroll
    for (int k = 0; k < TU; ++k) { xb1[k] = xin1[(size_t)k * d]; xb2[k] = xin2[(size_t)k * d]; }

    Base2 cur = make_base(xb1[0], xb2[0]);

    for (int g = 0; g < T; g += TU) {
        float xn1[TU], xn2[TU];
        if (g + TU < T) {
#pragma unroll
            for (int k = 0; k < TU; ++k) {
                xn1[k] = xin1[(size_t)(g + TU + k) * d];
                xn2[k] = xin2[(size_t)(g + TU + k) * d];
            }
        } else {
#pragma unroll
            for (int k = 0; k < TU; ++k) { xn1[k] = 0.f; xn2[k] = 0.f; }
        }

#pragma unroll
        for (int k = 0; k < TU; ++k) {
            // next timestep's base, issued early to hide under unfold stalls
            const float xa = (k + 1 < TU) ? xb1[k + 1] : xn1[0];
            const float xb = (k + 1 < TU) ? xb2[k + 1] : xn2[0];
            const Base2 nxt = make_base(xa, xb);

#pragma unroll
            for (int uu = 0; uu < ODE_UNFOLDS; ++uu) {
                const v2f cn = cmuV * num;               // pk, parallel w/ rcp
                const v2f ts = AsV * num;
                const v2f to = AoV * num;
                const v2f argo = __builtin_elementwise_fma(to, r, CoV);
                const v2f args = __builtin_elementwise_fma(ts, r, CsV);

                const float eo0 = __builtin_amdgcn_exp2f(argo.x);
                const float eo1 = __builtin_amdgcn_exp2f(argo.y);
                const float es0 = __builtin_amdgcn_exp2f(args.x);
                const float es1 = __builtin_amdgcn_exp2f(args.y);
                const float ex0 = swap_pair(eo0);        // partner's exps
                const float ex1 = swap_pair(eo1);
                const v2f es = {es0, es1};
                const v2f ex = {ex0, ex1};

                const v2f tdb = __builtin_elementwise_fma(cn, r, cur.nbdb); // t+db
                const v2f pe  = es + v2f{1.f, 1.f};
                const v2f P1  = __builtin_elementwise_fma(cur.Ks, es, cur.K0);
                const v2f P2  = __builtin_elementwise_fma(cur.db, es, cur.Kx);
                const v2f Pp  = __builtin_elementwise_fma(pe, ex, pe); // (1+es)(1+ex)
                const v2f den = __builtin_elementwise_fma(P2, ex, P1);

                num = __builtin_elementwise_fma(tdb, Pp, -den);  // (t+db)P - den'
                r.x = __builtin_amdgcn_rcpf(den.x);
                r.y = __builtin_amdgcn_rcpf(den.y);
            }

            cur = nxt;
        }

#pragma unroll
        for (int k = 0; k < TU; ++k) { xb1[k] = xn1[k]; xb2[k] = xn2[k]; }
    }

    if (h == 0) {
        const float ow = output_w[j], ob = output_b[j];
        out[(size_t)b1 * d + j] = fmaf(num.x * r.x, ow, ob);
        out[(size_t)b2 * d + j] = fmaf(num.y * r.y, ow, ob);
    }
}

extern "C" void kernel_launch(void* const* d_in, const int* in_sizes, int n_in,
                              void* d_out, int out_size, void* d_ws, size_t ws_size,
                              hipStream_t stream) {
    const float* inputs   = (const float*)d_in[0];
    const float* input_w  = (const float*)d_in[1];
    const float* input_b  = (const float*)d_in[2];
    const float* output_w = (const float*)d_in[3];
    const float* output_b = (const float*)d_in[4];
    const float* gleak    = (const float*)d_in[5];
    const float* vleak    = (const float*)d_in[6];
    const float* cm       = (const float*)d_in[7];
    const float* w        = (const float*)d_in[8];
    const float* mu       = (const float*)d_in[9];
    const float* sigma    = (const float*)d_in[10];
    const float* erev     = (const float*)d_in[11];
    const float* sw       = (const float*)d_in[12];
    const float* smu      = (const float*)d_in[13];
    const float* ssig     = (const float*)d_in[14];
    const float* serev    = (const float*)d_in[15];
    float* out = (float*)d_out;

    const int d = in_sizes[1];            // input_w has shape (d,)
    const int B = out_size / d;           // out is (B, d)
    const int T = in_sizes[0] / (B * d);  // inputs is (B, T, d)

    const int Bh = (B + 1) >> 1;
    const int total = Bh * 2 * d;         // one thread per (half-batch, unit)
    const int block = 64;
    const int grid = (total + block - 1) / block;
    ltc_twin_kernel<<<grid, block, 0, stream>>>(
        inputs, input_w, input_b, output_w, output_b,
        gleak, vleak, cm, w, mu, sigma, erev,
        sw, smu, ssig, serev, out, B, T, d);
}

// Round 11
// 36.229 us; speedup vs baseline: 1.3651x; 1.3651x over previous
//
#include <hip/hip_runtime.h>

#define ODE_UNFOLDS 6
#define LTC_EPS 1e-8f

// One lane per (batch b, unit u); adjacent lanes hold the coupled pair {j,j+d}.
// State: (num, r), v = num*r.  [Best structure: R8, reverted from R9 twin.]
//
// Wiring identity (MemoryCellWiring): erev = -mask, sensory_erev = +smask,
// so with num/den scaled through by P = (1+es)(1+ex):
//   den' = K0 + Ks*es + Kx*ex + db*es*ex      (Horner by late ex)
//   num' = (t+db)*P - den'                    (numerator collapses)
// where t = cm*v + nb, nb+db = (gv+den0) + 2*sW*ss is one base fma.
// Per unfold: 2 exp + 1 rcp (trans; ~40cy latency, ~14cy issue each) +
// ~10 full-rate ops. Chain: rcp->fma->exp->fma->fma ~= 104cy (measured 113).
//
// R10 micro-variant: exchange the cross-synapse ARGUMENT (post-fma DPP)
// instead of the exp result (post-trans DPP) - avoids trans->DPP hazard;
// each lane evaluates its incoming-cross exp locally.

__device__ __forceinline__ float swap_pair(float x) {
    // quad_perm [1,0,3,2] : lane XOR 1, full-rate v_mov_b32 dpp
    return __int_as_float(
        __builtin_amdgcn_mov_dpp(__float_as_int(x), 0xB1, 0xF, 0xF, true));
}

struct Base { float db, nbdb, K0, Ks, Kx; };

__global__ __launch_bounds__(64)
void ltc_lane_kernel(const float* __restrict__ inputs,
                     const float* __restrict__ input_w, const float* __restrict__ input_b,
                     const float* __restrict__ output_w, const float* __restrict__ output_b,
                     const float* __restrict__ gleak, const float* __restrict__ vleak,
                     const float* __restrict__ cm,
                     const float* __restrict__ w, const float* __restrict__ mu,
                     const float* __restrict__ sigma, const float* __restrict__ erev,
                     const float* __restrict__ sw, const float* __restrict__ smu,
                     const float* __restrict__ ssig, const float* __restrict__ serev,
                     float* __restrict__ out,
                     int B, int T, int d)
{
    const int tid = blockIdx.x * blockDim.x + threadIdx.x;
    const int units = 2 * d;
    if (tid >= B * units) return;

    const int pairIdx = tid >> 1;
    const int h = tid & 1;                 // 0 -> unit j, 1 -> unit j+d
    const int b = pairIdx / d;
    const int j = pairIdx - b * d;
    const int u  = j + h * d;              // my unit
    const int pu = j + (1 - h) * d;        // partner unit

    const float LOG2E = 1.4426950408889634f;

    // self synapse u->u
    float A_s, C_s, W_s;
    {
        int i = u * units + u;
        float sg = sigma[i], m = mu[i];
        A_s = -sg * LOG2E; C_s = m * sg * LOG2E;
        W_s = w[i] * (-erev[i]);           // = +W (erev = -1 here)
    }
    // incoming cross synapse pu->u: weights only; its exp ARG comes from the
    // partner via DPP (partner computes A,C for its outgoing synapse = this one)
    float W_c;
    {
        int i = pu * units + u;
        W_c = w[i] * (-erev[i]);
    }
    // outgoing cross synapse u->pu: we compute its exp ARG from our own state
    float A_o, C_o;
    {
        int i = u * units + pu;
        float sg = sigma[i], m = mu[i];
        A_o = -sg * LOG2E; C_o = m * sg * LOG2E;
    }
    const float Wsum = W_s + W_c;

    // sensory synapse j -> u (serev = +1), input affine folded in
    float siA, siC, sW;
    {
        int i = j * units + u;
        float sg = ssig[i], m = smu[i];
        float sA = -sg * LOG2E, sC = m * sg * LOG2E;
        const float iw = input_w[j], ib = input_b[j];
        siA = iw * sA; siC = ib * sA + sC;
        sW = sw[i] * serev[i];
    }

    const float cmu = cm[u] * (float)ODE_UNFOLDS;
    const float gl  = gleak[u];
    const float gv  = gl * vleak[u];
    const float den0 = cmu + gl + LTC_EPS;
    const float sW2 = 2.f * sW;
    const float gvden0 = gv + den0;

    const float* __restrict__ xin = inputs + (size_t)b * T * d + j;

    auto make_base = [&](float x) -> Base {
        const float e  = __builtin_amdgcn_exp2f(fmaf(x, siA, siC));
        const float ss = __builtin_amdgcn_rcpf(1.f + e);
        Base bb;
        bb.db   = fmaf(sW,  ss, den0);
        bb.nbdb = fmaf(sW2, ss, gvden0);   // nb + db in one fma
        bb.K0 = bb.db + Wsum;
        bb.Ks = bb.db + W_c;
        bb.Kx = bb.db + W_s;
        return bb;
    };

    // recurrence state: v = num * r
    float num = 0.f, r = 1.f;

    const int TU = 4;
    float xbuf[TU];
#pragma unroll
    for (int k = 0; k < TU; ++k) xbuf[k] = xin[(size_t)k * d];

    Base cur = make_base(xbuf[0]);

    for (int g = 0; g < T; g += TU) {
        float xnext[TU];
        if (g + TU < T) {
#pragma unroll
            for (int k = 0; k < TU; ++k) xnext[k] = xin[(size_t)(g + TU + k) * d];
        } else {
#pragma unroll
            for (int k = 0; k < TU; ++k) xnext[k] = 0.f;
        }

#pragma unroll
        for (int k = 0; k < TU; ++k) {
            // next timestep's base, issued early so it hides under unfold stalls
            const float xn1 = (k + 1 < TU) ? xbuf[k + 1] : xnext[0];
            const Base nxt = make_base(xn1);

#pragma unroll
            for (int uu = 0; uu < ODE_UNFOLDS; ++uu) {
                const float cn = cmu * num;          // parallel w/ rcp
                const float ts = A_s * num;
                const float to = A_o * num;
                const float argo = fmaf(to, r, C_o); // outgoing arg first
                const float args = fmaf(ts, r, C_s);
                const float argx = swap_pair(argo);  // partner's incoming arg
                const float es = __builtin_amdgcn_exp2f(args);
                const float ex = __builtin_amdgcn_exp2f(argx);

                const float tdb = fmaf(cn, r, cur.nbdb);  // t + db
                const float pe  = 1.f + es;
                const float P1  = fmaf(cur.Ks, es, cur.K0);
                const float P2  = fmaf(cur.db, es, cur.Kx);
                const float Pp  = fmaf(pe, ex, pe);       // (1+es)(1+ex)
                const float den = fmaf(P2, ex, P1);

                num = fmaf(tdb, Pp, -den);           // (t+db)*P - den'
                r   = __builtin_amdgcn_rcpf(den);
            }

            cur = nxt;
        }

#pragma unroll
        for (int k = 0; k < TU; ++k) xbuf[k] = xnext[k];
    }

    if (h == 0) {
        const float v = num * r;
        out[(size_t)b * d + j] = fmaf(v, output_w[j], output_b[j]);
    }
}

extern "C" void kernel_launch(void* const* d_in, const int* in_sizes, int n_in,
                              void* d_out, int out_size, void* d_ws, size_t ws_size,
                              hipStream_t stream) {
    const float* inputs   = (const float*)d_in[0];
    const float* input_w  = (const float*)d_in[1];
    const float* input_b  = (const float*)d_in[2];
    const float* output_w = (const float*)d_in[3];
    const float* output_b = (const float*)d_in[4];
    const float* gleak    = (const float*)d_in[5];
    const float* vleak    = (const float*)d_in[6];
    const float* cm       = (const float*)d_in[7];
    const float* w        = (const float*)d_in[8];
    const float* mu       = (const float*)d_in[9];
    const float* sigma    = (const float*)d_in[10];
    const float* erev     = (const float*)d_in[11];
    const float* sw       = (const float*)d_in[12];
    const float* smu      = (const float*)d_in[13];
    const float* ssig     = (const float*)d_in[14];
    const float* serev    = (const float*)d_in[15];
    float* out = (float*)d_out;

    const int d = in_sizes[1];            // input_w has shape (d,)
    const int B = out_size / d;           // out is (B, d)
    const int T = in_sizes[0] / (B * d);  // inputs is (B, T, d)

    const int total = B * 2 * d;          // one thread per (b, unit)
    const int block = 64;
    const int grid = (total + block - 1) / block;
    ltc_lane_kernel<<<grid, block, 0, stream>>>(
        inputs, input_w, input_b, output_w, output_b,
        gleak, vleak, cm, w, mu, sigma, erev,
        sw, smu, ssig, serev, out, B, T, d);
}